// Round 12
// baseline (394.665 us; speedup 1.0000x reference)
//
#include <hip/hip_runtime.h>
#include <hip/hip_bf16.h>

// DGLHGNNConv: Xv = degV * (H^T (degE * W * (H (X @ Wlin))))
// Round 20: R19 retry (compile fix: __builtin_nontemporal_* needs clang
// ext_vector types, not HIP_vector_type int4/ushort4).
// Theory unchanged: K4's gatherE is at the L2-fill wall (200MB FETCH =
// 8-XCD replication of 25.6MB Xp). Slice-major Xp (Xp[slice][node][16])
// + XCD-sliced gatherE (slice = bid&7): per-XCD working set 3.2MB < 4MB
// L2 -> random row reads become L2 hits. adjE via NT loads, Xe/adjV/out
// NT stores.
//   K0 k_init       : Wt = bf16(Wlin^T)
//   K1 k_gemm_histE : gemm (1563, slice-major Xp) || histE (256, 25KB)
//   K2 k_scanE_histV: scanE (98) || histV (1024, 25KB)
//   K3 k_scatE_scanV: scatterE (256, 25KB) || scanV (391)
//   K4 k_gathE_scatV: gatherE XCD-sliced (1568) || scatterV 4 ranges (1024)
//   K5 k_gatherV    : full, 16-deep (6250)
// Xe aliases histE8 (dead after K3). ZERO global atomics.

#define CAPE 128   // Poisson(64) hyperedge degree; P(overflow) ~ 1e-12
#define CAPV 64    // Poisson(16) node degree;     P(overflow) ~ 1e-20
#define LDK  136   // 128 + 8 u16 pad: 16B-aligned rows, conflict-free b128
#define RW   6250  // histogram range width in u32 words (25KB LDS)

typedef __attribute__((ext_vector_type(8))) short bf16x8;
typedef __attribute__((ext_vector_type(4))) float f32x4;
typedef __attribute__((ext_vector_type(8))) float f32x8;
typedef __attribute__((ext_vector_type(4))) int i32x4;
typedef __attribute__((ext_vector_type(4))) unsigned short u16x4;

__device__ __forceinline__ unsigned short f32_to_bf16(float f) {
    unsigned int u = __float_as_uint(f);
    u += 0x7FFFu + ((u >> 16) & 1u);   // RNE
    return (unsigned short)(u >> 16);
}
__device__ __forceinline__ float bf16_to_f32(unsigned short h) {
    return __uint_as_float(((unsigned int)h) << 16);
}

// ================= device bodies =================

// 16-deep batched per-bucket prefix over chunks (verified R15-R18)
__device__ __forceinline__ void scan_body(unsigned char* __restrict__ h8, int n,
                                          int b, int nch, int* __restrict__ cnt) {
    int run = 0;
    for (int c0 = 0; c0 < nch; c0 += 16) {      // nch is a multiple of 16
        unsigned char v[16];
#pragma unroll
        for (int j = 0; j < 16; ++j)
            v[j] = h8[(long)(c0 + j) * n + b];
        unsigned char w[16];
#pragma unroll
        for (int j = 0; j < 16; ++j) {
            w[j] = (unsigned char)run;
            run += v[j];
        }
#pragma unroll
        for (int j = 0; j < 16; ++j)
            h8[(long)(c0 + j) * n + b] = w[j];
    }
    cnt[b] = run;
}

// per-(chunk,range) LDS u8 histogram (verified R14-R18)
__device__ __forceinline__ void hist_body(unsigned int* __restrict__ s32,
                                          const int* __restrict__ key, int nnz,
                                          unsigned int* __restrict__ hist,
                                          int n4, int ch, int c, int w0, int w1,
                                          int tid) {
    const int nw = w1 - w0;
    for (int i = tid; i < nw; i += 256) s32[i] = 0;
    __syncthreads();
    int e0 = c * ch, e1 = e0 + ch; if (e1 > nnz) e1 = nnz;
    for (int e = e0 + tid; e < e1; e += 256) {
        int k = key[e];
        int w = k >> 2;
        if (w >= w0 && w < w1)
            atomicAdd(&s32[w - w0], 1u << ((k & 3) * 8));
    }
    __syncthreads();
    for (int i = tid; i < nw; i += 256)
        hist[(long)c * n4 + w0 + i] = s32[i];
}

// scatterV range body: counters preloaded WITH bases (verified R16-R18)
__device__ __forceinline__ void scatV_body(unsigned int* __restrict__ c32,
                                           const int* __restrict__ src,
                                           const int* __restrict__ dst, int nnz,
                                           const unsigned char* __restrict__ histV8,
                                           unsigned short* __restrict__ adjV,
                                           int nV4, int chv, int c, int r, int tid) {
    const int w0 = r * RW;
    int w1 = w0 + RW; if (w1 > nV4) w1 = nV4;
    const int nw = w1 - w0;
    const unsigned int* brow = (const unsigned int*)histV8 + (long)c * nV4 + w0;
    for (int i = tid; i < nw; i += 256) c32[i] = brow[i];   // counters = bases
    __syncthreads();
    int e0 = c * chv, e1 = e0 + chv; if (e1 > nnz) e1 = nnz;
    for (int e = e0 + tid; e < e1; e += 256) {
        int k = src[e];
        int w = k >> 2;
        if (w < w0 || w >= w1) continue;
        int sh = (k & 3) * 8;
        unsigned int old = atomicAdd(&c32[w - w0], 1u << sh);
        int slot = (old >> sh) & 0xFF;                      // base + rank
        if (slot < CAPV)
            __builtin_nontemporal_store((unsigned short)dst[e],
                                        adjV + (long)k * CAPV + slot);
    }
}

// gatherE XCD-sliced: slice = bid&7, 2 thr/hedge, 8 bf16 cols/thread.
// Xp is slice-major: Xp[slice*sstride + node*16 + c]. adjE via NT loads.
__device__ __forceinline__ void gatherE_sliced(int bid, int tid,
                                               const unsigned short* __restrict__ Xp,
                                               const int* __restrict__ cntE,
                                               const int* __restrict__ adjE,
                                               const float* __restrict__ degE,
                                               const float* __restrict__ Wbuf,
                                               unsigned short* __restrict__ Xe,
                                               int nE, long sstride) {
    const int slice = bid & 7;
    int e = ((bid >> 3) << 7) + (tid >> 1);
    if (e >= nE) return;
    const int c = (tid & 1) << 3;               // 0 or 8 within slice
    const unsigned short* Xs = Xp + (long)slice * sstride;
    int len = cntE[e];
    if (len > CAPE) len = CAPE;
    const int* adj = adjE + (long)e * CAPE;
    float acc[8];
#pragma unroll
    for (int q = 0; q < 8; ++q) acc[q] = 0.f;

    int i = 0;
    for (; i + 16 <= len; i += 16) {
        i32x4 a0 = __builtin_nontemporal_load((const i32x4*)(adj + i));
        i32x4 a1 = __builtin_nontemporal_load((const i32x4*)(adj + i + 4));
        i32x4 a2 = __builtin_nontemporal_load((const i32x4*)(adj + i + 8));
        i32x4 a3 = __builtin_nontemporal_load((const i32x4*)(adj + i + 12));
        int v[16] = {a0.x, a0.y, a0.z, a0.w, a1.x, a1.y, a1.z, a1.w,
                     a2.x, a2.y, a2.z, a2.w, a3.x, a3.y, a3.z, a3.w};
        bf16x8 h[16];
#pragma unroll
        for (int j = 0; j < 16; ++j)
            h[j] = *(const bf16x8*)(Xs + (long)v[j] * 16 + c);
#pragma unroll
        for (int j = 0; j < 16; ++j)
#pragma unroll
            for (int q = 0; q < 8; ++q)
                acc[q] += bf16_to_f32((unsigned short)h[j][q]);
    }
    for (; i + 8 <= len; i += 8) {
        i32x4 a0 = __builtin_nontemporal_load((const i32x4*)(adj + i));
        i32x4 a1 = __builtin_nontemporal_load((const i32x4*)(adj + i + 4));
        int v[8] = {a0.x, a0.y, a0.z, a0.w, a1.x, a1.y, a1.z, a1.w};
        bf16x8 h[8];
#pragma unroll
        for (int j = 0; j < 8; ++j)
            h[j] = *(const bf16x8*)(Xs + (long)v[j] * 16 + c);
#pragma unroll
        for (int j = 0; j < 8; ++j)
#pragma unroll
            for (int q = 0; q < 8; ++q)
                acc[q] += bf16_to_f32((unsigned short)h[j][q]);
    }
    for (; i + 4 <= len; i += 4) {
        i32x4 a0 = __builtin_nontemporal_load((const i32x4*)(adj + i));
        int v[4] = {a0.x, a0.y, a0.z, a0.w};
        bf16x8 h[4];
#pragma unroll
        for (int j = 0; j < 4; ++j)
            h[j] = *(const bf16x8*)(Xs + (long)v[j] * 16 + c);
#pragma unroll
        for (int j = 0; j < 4; ++j)
#pragma unroll
            for (int q = 0; q < 8; ++q)
                acc[q] += bf16_to_f32((unsigned short)h[j][q]);
    }
    for (; i < len; ++i) {
        int v = adj[i];
        bf16x8 h = *(const bf16x8*)(Xs + (long)v * 16 + c);
#pragma unroll
        for (int q = 0; q < 8; ++q)
            acc[q] += bf16_to_f32((unsigned short)h[q]);
    }

    float sc = degE[e] * Wbuf[e];
    bf16x8 o;
#pragma unroll
    for (int q = 0; q < 8; ++q) o[q] = (short)f32_to_bf16(acc[q] * sc);
    __builtin_nontemporal_store(o, (bf16x8*)(Xe + (long)e * 128 + slice * 16 + c));
}

// gatherV: 16 thr/node, 16-deep batched prefetch (verified R18)
__device__ __forceinline__ void gatherV_body(int id, int tid,
                                             const unsigned short* __restrict__ Xe,
                                             const int* __restrict__ cntV,
                                             const unsigned short* __restrict__ adjV,
                                             const float* __restrict__ degV,
                                             float* __restrict__ out,
                                             int vLo, int vHi) {
    int t = id * 256 + tid;
    int v = vLo + (t >> 4);
    if (v >= vHi) return;
    int c = (t & 15) << 3;
    int len = cntV[v];
    if (len > CAPV) len = CAPV;
    const unsigned short* adj = adjV + (long)v * CAPV;
    float acc[8];
#pragma unroll
    for (int q = 0; q < 8; ++q) acc[q] = 0.f;

    int i = 0;
    for (; i + 16 <= len; i += 16) {
        u16x4 a0 = *(const u16x4*)(adj + i);
        u16x4 a1 = *(const u16x4*)(adj + i + 4);
        u16x4 a2 = *(const u16x4*)(adj + i + 8);
        u16x4 a3 = *(const u16x4*)(adj + i + 12);
        int e[16] = {a0.x, a0.y, a0.z, a0.w, a1.x, a1.y, a1.z, a1.w,
                     a2.x, a2.y, a2.z, a2.w, a3.x, a3.y, a3.z, a3.w};
        bf16x8 h[16];
#pragma unroll
        for (int j = 0; j < 16; ++j)
            h[j] = *(const bf16x8*)(Xe + (long)e[j] * 128 + c);
#pragma unroll
        for (int j = 0; j < 16; ++j)
#pragma unroll
            for (int q = 0; q < 8; ++q)
                acc[q] += bf16_to_f32((unsigned short)h[j][q]);
    }
    for (; i + 8 <= len; i += 8) {
        u16x4 a0 = *(const u16x4*)(adj + i);
        u16x4 a1 = *(const u16x4*)(adj + i + 4);
        int e[8] = {a0.x, a0.y, a0.z, a0.w, a1.x, a1.y, a1.z, a1.w};
        bf16x8 h[8];
#pragma unroll
        for (int j = 0; j < 8; ++j)
            h[j] = *(const bf16x8*)(Xe + (long)e[j] * 128 + c);
#pragma unroll
        for (int j = 0; j < 8; ++j)
#pragma unroll
            for (int q = 0; q < 8; ++q)
                acc[q] += bf16_to_f32((unsigned short)h[j][q]);
    }
    for (; i + 4 <= len; i += 4) {
        u16x4 a0 = *(const u16x4*)(adj + i);
        int e[4] = {a0.x, a0.y, a0.z, a0.w};
        bf16x8 h[4];
#pragma unroll
        for (int j = 0; j < 4; ++j)
            h[j] = *(const bf16x8*)(Xe + (long)e[j] * 128 + c);
#pragma unroll
        for (int j = 0; j < 4; ++j)
#pragma unroll
            for (int q = 0; q < 8; ++q)
                acc[q] += bf16_to_f32((unsigned short)h[j][q]);
    }
    for (; i < len; ++i) {
        int e = adj[i];
        bf16x8 h = *(const bf16x8*)(Xe + (long)e * 128 + c);
#pragma unroll
        for (int q = 0; q < 8; ++q)
            acc[q] += bf16_to_f32((unsigned short)h[q]);
    }

    float sc = degV[v];
    f32x8 o;
#pragma unroll
    for (int q = 0; q < 8; ++q) o[q] = acc[q] * sc;
    __builtin_nontemporal_store(o, (f32x8*)(out + (long)v * 128 + c));
}

// ================= kernels =================

// K0: Wt[n][k] = bf16(Wlin[k][n])
__global__ __launch_bounds__(256) void k_init(const float* __restrict__ Wl,
                                              unsigned short* __restrict__ Wt) {
    int idx = blockIdx.x * 256 + threadIdx.x;   // 64 blocks x 256
    if (idx < 128 * 128) {
        int n = idx >> 7, k = idx & 127;
        Wt[idx] = f32_to_bf16(Wl[k * 128 + n]);
    }
}

// K1: gemm (verified body; Xp written slice-major) || histE (single range)
__global__ __launch_bounds__(256) void k_gemm_histE(
    const float* __restrict__ X, const unsigned short* __restrict__ Wt,
    unsigned short* __restrict__ Xp, int nrows, int nGemm,
    const int* __restrict__ keyE, int nnz,
    unsigned int* __restrict__ histE32, int nE4, int che, int nchE)
{
    __shared__ union {
        struct { unsigned short Xs[64 * LDK]; unsigned short Wt[128 * LDK]; } g;
        unsigned int s32[RW];
    } sm;   // 52,224 B -> 3 blocks/CU

    int bid = blockIdx.x;
    const int tid = threadIdx.x;

    if (bid < nGemm) {
        const int row0 = bid * 64;
        for (int base = tid * 4; base < 64 * 128; base += 1024) {
            int r = base >> 7, c = base & 127;
            float4 v = make_float4(0.f, 0.f, 0.f, 0.f);
            if (row0 + r < nrows) v = *(const float4*)(X + (long)(row0 + r) * 128 + c);
            ushort4 h;
            h.x = f32_to_bf16(v.x); h.y = f32_to_bf16(v.y);
            h.z = f32_to_bf16(v.z); h.w = f32_to_bf16(v.w);
            *(ushort4*)(sm.g.Xs + r * LDK + c) = h;
        }
        for (int base = tid * 4; base < 128 * 128; base += 1024) {
            int n = base >> 7, k = base & 127;
            ushort4 h = *(const ushort4*)(Wt + base);
            *(ushort4*)(sm.g.Wt + n * LDK + k) = h;
        }
        __syncthreads();

        const int w    = tid >> 6;
        const int lane = tid & 63;
        const int m    = lane & 15;
        const int quad = lane >> 4;

        f32x4 acc[8];
#pragma unroll
        for (int ct = 0; ct < 8; ++ct) acc[ct] = (f32x4){0.f, 0.f, 0.f, 0.f};

#pragma unroll
        for (int kk = 0; kk < 4; ++kk) {
            bf16x8 a = *(const bf16x8*)(sm.g.Xs + (w * 16 + m) * LDK + kk * 32 + quad * 8);
#pragma unroll
            for (int ct = 0; ct < 8; ++ct) {
                bf16x8 b = *(const bf16x8*)(sm.g.Wt + (ct * 16 + m) * LDK + kk * 32 + quad * 8);
                acc[ct] = __builtin_amdgcn_mfma_f32_16x16x32_bf16(a, b, acc[ct], 0, 0, 0);
            }
        }
        // slice-major store: Xp[ct][row][m], slice stride = nrows*16
#pragma unroll
        for (int ct = 0; ct < 8; ++ct) {
#pragma unroll
            for (int r = 0; r < 4; ++r) {
                int row = row0 + w * 16 + quad * 4 + r;
                if (row < nrows)
                    Xp[(long)ct * nrows * 16 + (long)row * 16 + m] =
                        f32_to_bf16(acc[ct][r]);
            }
        }
        return;
    }

    int c = bid - nGemm;
    if (c < nchE)
        hist_body(sm.s32, keyE, nnz, histE32, nE4, che, c, 0, nE4, tid);
}

// K2: scanE || histV (4 ranges, 25KB)
__global__ __launch_bounds__(256) void k_scanE_histV(
    unsigned char* __restrict__ histE8, int* __restrict__ cntE,
    int nE, int nchE, int nScanE,
    const int* __restrict__ keyV, int nnz,
    unsigned int* __restrict__ histV32, int nV4, int chv, int nchV)
{
    __shared__ unsigned int s32[RW];   // 25KB
    int bid = blockIdx.x;
    const int tid = threadIdx.x;
    if (bid < nScanE) {
        int t = bid * 256 + tid;
        if (t < nE) scan_body(histE8, nE, t, nchE, cntE);
        return;
    }
    bid -= nScanE;
    const int c = bid % nchV, r = bid / nchV;
    const int w0 = r * RW;
    int w1 = w0 + RW; if (w1 > nV4) w1 = nV4;
    hist_body(s32, keyV, nnz, histV32, nV4, chv, c, w0, w1, tid);
}

// K3: scatterE (base-in-counter, 25KB) || scanV
__global__ __launch_bounds__(256) void k_scatE_scanV(
    const int* __restrict__ src, const int* __restrict__ dst, int nnz,
    const unsigned char* __restrict__ histE8, int* __restrict__ adjE,
    int nE4, int che, int nchE,
    unsigned char* __restrict__ histV8, int* __restrict__ cntV, int nV, int nchV)
{
    __shared__ unsigned int c32[RW];    // 25KB
    int bid = blockIdx.x;
    const int tid = threadIdx.x;
    if (bid < nchE) {
        const int c = bid;
        const unsigned int* brow = (const unsigned int*)histE8 + (long)c * nE4;
        for (int i = tid; i < nE4; i += 256) c32[i] = brow[i];  // counters = bases
        __syncthreads();
        int e0 = c * che, e1 = e0 + che; if (e1 > nnz) e1 = nnz;
        for (int e = e0 + tid; e < e1; e += 256) {
            int k = dst[e];
            int sh = (k & 3) * 8;
            unsigned int old = atomicAdd(&c32[k >> 2], 1u << sh);
            int slot = (old >> sh) & 0xFF;                      // base + rank
            if (slot < CAPE) adjE[(long)k * CAPE + slot] = src[e];
        }
        return;
    }
    int t = (bid - nchE) * 256 + tid;
    if (t < nV) scan_body(histV8, nV, t, nchV, cntV);
}

// K4: gatherE XCD-sliced || scatterV ALL ranges — 25KB LDS
__global__ __launch_bounds__(256) void k_gathE_scatV(
    const unsigned short* __restrict__ Xp, const int* __restrict__ cntE,
    const int* __restrict__ adjE, const float* __restrict__ degE,
    const float* __restrict__ Wbuf, unsigned short* __restrict__ Xe,
    int nE, int nGathE, long sstride,
    const int* __restrict__ src, const int* __restrict__ dst, int nnz,
    const unsigned char* __restrict__ histV8, unsigned short* __restrict__ adjV,
    int nV4, int chv, int nchV)
{
    __shared__ unsigned int c32[RW];   // 25KB
    int bid = blockIdx.x;
    const int tid = threadIdx.x;
    if (bid < nGathE) {
        gatherE_sliced(bid, tid, Xp, cntE, adjE, degE, Wbuf, Xe, nE, sstride);
        return;
    }
    bid -= nGathE;
    const int c = bid % nchV, r = bid / nchV;   // r in [0, nrV)
    scatV_body(c32, src, dst, nnz, histV8, adjV, nV4, chv, c, r, tid);
}

// K5: gatherV (full range, 16-deep)
__global__ __launch_bounds__(256) void k_gatherV(const unsigned short* __restrict__ Xe,
                                                 const int* __restrict__ cntV,
                                                 const unsigned short* __restrict__ adjV,
                                                 const float* __restrict__ degV,
                                                 float* __restrict__ out,
                                                 int vLo, int vHi) {
    gatherV_body(blockIdx.x, threadIdx.x, Xe, cntV, adjV, degV, out, vLo, vHi);
}

// ---------------- Atomic fallback (round-1, known-good) ----------------
__global__ __launch_bounds__(256) void zero_f4(float4* __restrict__ p, int n4) {
    int i = blockIdx.x * 256 + threadIdx.x;
    if (i < n4) p[i] = make_float4(0.f, 0.f, 0.f, 0.f);
}

__global__ __launch_bounds__(256) void gemm_xw_f32(const float* __restrict__ X,
                                                   const float* __restrict__ Wl,
                                                   float* __restrict__ Xp,
                                                   int nrows) {
    __shared__ float Xs[32 * 128];
    const int tid = threadIdx.x;
    const int row0 = blockIdx.x * 32;
    for (int i = tid * 4; i < 32 * 128; i += 256 * 4) {
        int r = row0 + (i >> 7);
        float4 v = make_float4(0.f, 0.f, 0.f, 0.f);
        if (r < nrows) v = *(const float4*)(X + (long)row0 * 128 + i);
        *(float4*)(Xs + i) = v;
    }
    __syncthreads();
    const int col = tid & 127;
    const int rg  = (tid >> 7) * 16;
    float acc[16];
#pragma unroll
    for (int r = 0; r < 16; ++r) acc[r] = 0.f;
    for (int k = 0; k < 128; k += 4) {
        const float w0 = Wl[(k + 0) * 128 + col];
        const float w1 = Wl[(k + 1) * 128 + col];
        const float w2 = Wl[(k + 2) * 128 + col];
        const float w3 = Wl[(k + 3) * 128 + col];
#pragma unroll
        for (int r = 0; r < 16; ++r) {
            float4 x = *(const float4*)(Xs + (rg + r) * 128 + k);
            acc[r] = fmaf(x.w, w3, fmaf(x.z, w2, fmaf(x.y, w1, fmaf(x.x, w0, acc[r]))));
        }
    }
#pragma unroll
    for (int r = 0; r < 16; ++r) {
        int row = row0 + rg + r;
        if (row < nrows) Xp[(long)row * 128 + col] = acc[r];
    }
}

__global__ __launch_bounds__(256) void scatter_to_hedges(const float* __restrict__ Xp,
                                                         const int* __restrict__ src,
                                                         const int* __restrict__ dst,
                                                         float* __restrict__ Xe,
                                                         int nnz) {
    int t = blockIdx.x * 256 + threadIdx.x;
    int e = t >> 5;
    if (e >= nnz) return;
    int c = (t & 31) << 2;
    int s = src[e], d = dst[e];
    float4 v = *(const float4*)(Xp + (long)s * 128 + c);
    float* o = Xe + (long)d * 128 + c;
    atomicAdd(o + 0, v.x); atomicAdd(o + 1, v.y);
    atomicAdd(o + 2, v.z); atomicAdd(o + 3, v.w);
}

__global__ __launch_bounds__(256) void scatter_to_nodes(const float* __restrict__ Xe,
                                                        const int* __restrict__ src,
                                                        const int* __restrict__ dst,
                                                        const float* __restrict__ degE,
                                                        const float* __restrict__ Wbuf,
                                                        const float* __restrict__ degV,
                                                        float* __restrict__ out,
                                                        int nnz) {
    int t = blockIdx.x * 256 + threadIdx.x;
    int e = t >> 5;
    if (e >= nnz) return;
    int c = (t & 31) << 2;
    int s = src[e], d = dst[e];
    float sc = degE[d] * Wbuf[d] * degV[s];
    float4 v = *(const float4*)(Xe + (long)d * 128 + c);
    float* o = out + (long)s * 128 + c;
    atomicAdd(o + 0, v.x * sc); atomicAdd(o + 1, v.y * sc);
    atomicAdd(o + 2, v.z * sc); atomicAdd(o + 3, v.w * sc);
}

extern "C" void kernel_launch(void* const* d_in, const int* in_sizes, int n_in,
                              void* d_out, int out_size, void* d_ws, size_t ws_size,
                              hipStream_t stream) {
    const float* X    = (const float*)d_in[0];
    const float* Wlin = (const float*)d_in[1];
    const float* degE = (const float*)d_in[2];
    const float* degV = (const float*)d_in[3];
    const float* Wbuf = (const float*)d_in[4];
    const int* g1_src = (const int*)d_in[5];
    const int* g1_dst = (const int*)d_in[6];

    const int nE  = in_sizes[2];   // 25000
    const int nV  = in_sizes[3];   // 100000
    const int nnz = in_sizes[5];   // 1600000

    float* out = (float*)d_out;
    char* ws = (char*)d_ws;

    auto layout_size = [&](int cE, int cV) -> size_t {
        size_t o = 0;
        o += (size_t)nE * CAPE * 4;                 // adjE
        o += (size_t)nV * CAPV * 2;                 // adjV
        o += (size_t)nE * 4 + (size_t)nV * 4;       // cntE, cntV
        size_t he = (size_t)cE * nE;
        size_t xe = (size_t)nE * 128 * 2;
        o += (he > xe) ? he : xe;                   // histE8 (reused as Xe)
        o += (size_t)cV * nV;                       // histV8
        o += 128 * 128 * 2;                         // Wt
        o += 4096;                                  // alignment slack
        return o;
    };

    // launch-width cascade (all values multiples of 16)
    int nchE = 256, nchV = 256;
    if (layout_size(nchE, nchV) > ws_size) { nchE = 256; nchV = 128; }
    if (layout_size(nchE, nchV) > ws_size) { nchE = 128; nchV = 128; }
    if (layout_size(nchE, nchV) > ws_size) { nchE = 64;  nchV = 64;  }

    const int nE4 = nE >> 2, nV4 = nV >> 2;
    const bool eligible = ((nE & 3) == 0) && ((nV & 3) == 0) && (nE4 <= RW) &&
                          layout_size(nchE, nchV) <= ws_size;

    if (eligible) {
        size_t boff = 0;
        auto alloc = [&](size_t bytes) -> char* {
            char* p = ws + boff;
            boff += (bytes + 255) & ~(size_t)255;
            return p;
        };
        int* adjE            = (int*)alloc((size_t)nE * CAPE * 4);
        unsigned short* adjV = (unsigned short*)alloc((size_t)nV * CAPV * 2);
        int* cntE            = (int*)alloc((size_t)nE * 4);
        int* cntV            = (int*)alloc((size_t)nV * 4);
        size_t he = (size_t)nchE * nE;
        size_t xe = (size_t)nE * 128 * 2;
        char* region1         = alloc((he > xe) ? he : xe);
        unsigned char* histE8 = (unsigned char*)region1;
        unsigned short* Xe    = (unsigned short*)region1;  // reused after K3
        unsigned char* histV8 = (unsigned char*)alloc((size_t)nchV * nV);
        unsigned short* Wt    = (unsigned short*)alloc((size_t)128 * 128 * 2);

        unsigned short* Xp_bf = (unsigned short*)d_out;    // staged in d_out (slice-major)

        const int nrV = (nV4 + RW - 1) / RW;               // 4
        const int che = (nnz + nchE - 1) / nchE;
        const int chv = (nnz + nchV - 1) / nchV;
        const long sstride = (long)nV * 16;                // Xp slice stride

        // K0: Wt transpose
        k_init<<<64, 256, 0, stream>>>(Wlin, Wt);

        // K1: gemm || histE
        int nGemm = (nV + 63) / 64;                        // 1563
        k_gemm_histE<<<nGemm + nchE, 256, 0, stream>>>(
            X, Wt, Xp_bf, nV, nGemm,
            g1_dst, nnz, (unsigned int*)histE8, nE4, che, nchE);

        // K2: scanE || histV (4 ranges)
        int nScanE = (nE + 255) / 256;                     // 98
        k_scanE_histV<<<nScanE + nchV * nrV, 256, 0, stream>>>(
            histE8, cntE, nE, nchE, nScanE,
            g1_src, nnz, (unsigned int*)histV8, nV4, chv, nchV);

        // K3: scatterE || scanV
        int nScanV = (nV + 255) / 256;                     // 391
        k_scatE_scanV<<<nchE + nScanV, 256, 0, stream>>>(
            g1_src, g1_dst, nnz, histE8, adjE, nE4, che, nchE,
            histV8, cntV, nV, nchV);

        // K4: gatherE XCD-sliced || scatterV all ranges  (Xe overwrites histE8)
        int nGathE = 8 * ((nE + 127) / 128);               // 1568
        k_gathE_scatV<<<nGathE + nchV * nrV, 256, 0, stream>>>(
            Xp_bf, cntE, adjE, degE, Wbuf, Xe, nE, nGathE, sstride,
            g1_src, g1_dst, nnz, histV8, adjV, nV4, chv, nchV);

        // K5: gatherV (full)
        int nGathV = (nV * 16 + 255) / 256;                // 6250
        k_gatherV<<<nGathV, 256, 0, stream>>>(Xe, cntV, adjV, degV, out, 0, nV);
    } else {
        // --- atomic fallback (round-1) ---
        float* XeF = (float*)d_ws;
        float* Xp  = out;
        int n4 = nE * 128 / 4;
        zero_f4<<<(n4 + 255) / 256, 256, 0, stream>>>((float4*)XeF, n4);
        gemm_xw_f32<<<(nV + 31) / 32, 256, 0, stream>>>(X, Wlin, Xp, nV);
        long th = (long)nnz * 32;
        scatter_to_hedges<<<(int)((th + 255) / 256), 256, 0, stream>>>(Xp, g1_src, g1_dst,
                                                                       XeF, nnz);
        int m4 = out_size / 4;
        zero_f4<<<(m4 + 255) / 256, 256, 0, stream>>>((float4*)out, m4);
        scatter_to_nodes<<<(int)((th + 255) / 256), 256, 0, stream>>>(XeF, g1_src, g1_dst,
                                                                      degE, Wbuf, degV,
                                                                      out, nnz);
    }
}

// Round 13
// 326.149 us; speedup vs baseline: 1.2101x; 1.2101x over previous
//
#include <hip/hip_runtime.h>
#include <hip/hip_bf16.h>

// DGLHGNNConv: Xv = degV * (H^T (degE * W * (H (X @ Wlin))))
// Round 21: REVERT to R18 (verified best, 326.2us). R19/R20's XCD-sliced
// gatherE is falsified: bid&7->XCD affinity doesn't hold (32B-row locality
// loss) and NT adjE loads + 8x adjE re-read added 102MB uncached traffic
// (K4 79.6 -> 152us). R18's K4 is at the L2-miss-path wall (259MB @
// 3.25TB/s); all phases overlapped or at their own walls.
//   K0 k_init       : Wt = bf16(Wlin^T)
//   K1 k_gemm_histE : gemm (1563, 52KB) || histE (256, 25KB)
//   K2 k_scanE_histV: scanE (98) || histV (1024 = 4 ranges x 256, 25KB)
//   K3 k_scatE_scanV: scatterE (256, 25KB) || scanV (391)
//   K4 k_gathE_scatV: gatherE 16-deep (1563) || scatterV 4 ranges (1024)
//   K5 k_gatherV    : full, 16-deep (6250)
// Xe aliases histE8 (dead after K3). ZERO global atomics.

#define CAPE 128   // Poisson(64) hyperedge degree; P(overflow) ~ 1e-12
#define CAPV 64    // Poisson(16) node degree;     P(overflow) ~ 1e-20
#define LDK  136   // 128 + 8 u16 pad: 16B-aligned rows, conflict-free b128
#define RW   6250  // histogram range width in u32 words (25KB LDS)

typedef __attribute__((ext_vector_type(8))) short bf16x8;
typedef __attribute__((ext_vector_type(4))) float f32x4;
typedef __attribute__((ext_vector_type(8))) float f32x8;

__device__ __forceinline__ unsigned short f32_to_bf16(float f) {
    unsigned int u = __float_as_uint(f);
    u += 0x7FFFu + ((u >> 16) & 1u);   // RNE
    return (unsigned short)(u >> 16);
}
__device__ __forceinline__ float bf16_to_f32(unsigned short h) {
    return __uint_as_float(((unsigned int)h) << 16);
}

// ================= device bodies =================

// 16-deep batched per-bucket prefix over chunks (verified R15-R18)
__device__ __forceinline__ void scan_body(unsigned char* __restrict__ h8, int n,
                                          int b, int nch, int* __restrict__ cnt) {
    int run = 0;
    for (int c0 = 0; c0 < nch; c0 += 16) {      // nch is a multiple of 16
        unsigned char v[16];
#pragma unroll
        for (int j = 0; j < 16; ++j)
            v[j] = h8[(long)(c0 + j) * n + b];
        unsigned char w[16];
#pragma unroll
        for (int j = 0; j < 16; ++j) {
            w[j] = (unsigned char)run;
            run += v[j];
        }
#pragma unroll
        for (int j = 0; j < 16; ++j)
            h8[(long)(c0 + j) * n + b] = w[j];
    }
    cnt[b] = run;
}

// per-(chunk,range) LDS u8 histogram (verified R14-R18)
__device__ __forceinline__ void hist_body(unsigned int* __restrict__ s32,
                                          const int* __restrict__ key, int nnz,
                                          unsigned int* __restrict__ hist,
                                          int n4, int ch, int c, int w0, int w1,
                                          int tid) {
    const int nw = w1 - w0;
    for (int i = tid; i < nw; i += 256) s32[i] = 0;
    __syncthreads();
    int e0 = c * ch, e1 = e0 + ch; if (e1 > nnz) e1 = nnz;
    for (int e = e0 + tid; e < e1; e += 256) {
        int k = key[e];
        int w = k >> 2;
        if (w >= w0 && w < w1)
            atomicAdd(&s32[w - w0], 1u << ((k & 3) * 8));
    }
    __syncthreads();
    for (int i = tid; i < nw; i += 256)
        hist[(long)c * n4 + w0 + i] = s32[i];
}

// scatterV range body: counters preloaded WITH bases (verified R16-R18)
__device__ __forceinline__ void scatV_body(unsigned int* __restrict__ c32,
                                           const int* __restrict__ src,
                                           const int* __restrict__ dst, int nnz,
                                           const unsigned char* __restrict__ histV8,
                                           unsigned short* __restrict__ adjV,
                                           int nV4, int chv, int c, int r, int tid) {
    const int w0 = r * RW;
    int w1 = w0 + RW; if (w1 > nV4) w1 = nV4;
    const int nw = w1 - w0;
    const unsigned int* brow = (const unsigned int*)histV8 + (long)c * nV4 + w0;
    for (int i = tid; i < nw; i += 256) c32[i] = brow[i];   // counters = bases
    __syncthreads();
    int e0 = c * chv, e1 = e0 + chv; if (e1 > nnz) e1 = nnz;
    for (int e = e0 + tid; e < e1; e += 256) {
        int k = src[e];
        int w = k >> 2;
        if (w < w0 || w >= w1) continue;
        int sh = (k & 3) * 8;
        unsigned int old = atomicAdd(&c32[w - w0], 1u << sh);
        int slot = (old >> sh) & 0xFF;                      // base + rank
        if (slot < CAPV) adjV[(long)k * CAPV + slot] = (unsigned short)dst[e];
    }
}

// gatherE: 16 thr/hedge, bf16x8, 16-deep batched prefetch (verified R18)
__device__ __forceinline__ void gatherE_body(int id, int tid,
                                             const unsigned short* __restrict__ Xp,
                                             const int* __restrict__ cntE,
                                             const int* __restrict__ adjE,
                                             const float* __restrict__ degE,
                                             const float* __restrict__ Wbuf,
                                             unsigned short* __restrict__ Xe,
                                             int nE) {
    int t = id * 256 + tid;
    int e = t >> 4;
    if (e >= nE) return;
    int c = (t & 15) << 3;
    int len = cntE[e];
    if (len > CAPE) len = CAPE;
    const int* adj = adjE + (long)e * CAPE;
    float acc[8];
#pragma unroll
    for (int q = 0; q < 8; ++q) acc[q] = 0.f;

    int i = 0;
    for (; i + 16 <= len; i += 16) {
        int4 a0 = *(const int4*)(adj + i);
        int4 a1 = *(const int4*)(adj + i + 4);
        int4 a2 = *(const int4*)(adj + i + 8);
        int4 a3 = *(const int4*)(adj + i + 12);
        int v[16] = {a0.x, a0.y, a0.z, a0.w, a1.x, a1.y, a1.z, a1.w,
                     a2.x, a2.y, a2.z, a2.w, a3.x, a3.y, a3.z, a3.w};
        bf16x8 h[16];
#pragma unroll
        for (int j = 0; j < 16; ++j)
            h[j] = *(const bf16x8*)(Xp + (long)v[j] * 128 + c);
#pragma unroll
        for (int j = 0; j < 16; ++j)
#pragma unroll
            for (int q = 0; q < 8; ++q)
                acc[q] += bf16_to_f32((unsigned short)h[j][q]);
    }
    for (; i + 8 <= len; i += 8) {
        int4 a0 = *(const int4*)(adj + i);
        int4 a1 = *(const int4*)(adj + i + 4);
        int v[8] = {a0.x, a0.y, a0.z, a0.w, a1.x, a1.y, a1.z, a1.w};
        bf16x8 h[8];
#pragma unroll
        for (int j = 0; j < 8; ++j)
            h[j] = *(const bf16x8*)(Xp + (long)v[j] * 128 + c);
#pragma unroll
        for (int j = 0; j < 8; ++j)
#pragma unroll
            for (int q = 0; q < 8; ++q)
                acc[q] += bf16_to_f32((unsigned short)h[j][q]);
    }
    for (; i + 4 <= len; i += 4) {
        int4 a0 = *(const int4*)(adj + i);
        int v[4] = {a0.x, a0.y, a0.z, a0.w};
        bf16x8 h[4];
#pragma unroll
        for (int j = 0; j < 4; ++j)
            h[j] = *(const bf16x8*)(Xp + (long)v[j] * 128 + c);
#pragma unroll
        for (int j = 0; j < 4; ++j)
#pragma unroll
            for (int q = 0; q < 8; ++q)
                acc[q] += bf16_to_f32((unsigned short)h[j][q]);
    }
    for (; i < len; ++i) {
        int v = adj[i];
        bf16x8 h = *(const bf16x8*)(Xp + (long)v * 128 + c);
#pragma unroll
        for (int q = 0; q < 8; ++q)
            acc[q] += bf16_to_f32((unsigned short)h[q]);
    }

    float sc = degE[e] * Wbuf[e];
    bf16x8 o;
#pragma unroll
    for (int q = 0; q < 8; ++q) o[q] = (short)f32_to_bf16(acc[q] * sc);
    *(bf16x8*)(Xe + (long)e * 128 + c) = o;
}

// gatherV over node range: 16 thr/node, 16-deep batched prefetch (verified R18)
__device__ __forceinline__ void gatherV_body(int id, int tid,
                                             const unsigned short* __restrict__ Xe,
                                             const int* __restrict__ cntV,
                                             const unsigned short* __restrict__ adjV,
                                             const float* __restrict__ degV,
                                             float* __restrict__ out,
                                             int vLo, int vHi) {
    int t = id * 256 + tid;
    int v = vLo + (t >> 4);
    if (v >= vHi) return;
    int c = (t & 15) << 3;
    int len = cntV[v];
    if (len > CAPV) len = CAPV;
    const unsigned short* adj = adjV + (long)v * CAPV;
    float acc[8];
#pragma unroll
    for (int q = 0; q < 8; ++q) acc[q] = 0.f;

    int i = 0;
    for (; i + 16 <= len; i += 16) {
        ushort4 a0 = *(const ushort4*)(adj + i);
        ushort4 a1 = *(const ushort4*)(adj + i + 4);
        ushort4 a2 = *(const ushort4*)(adj + i + 8);
        ushort4 a3 = *(const ushort4*)(adj + i + 12);
        int e[16] = {a0.x, a0.y, a0.z, a0.w, a1.x, a1.y, a1.z, a1.w,
                     a2.x, a2.y, a2.z, a2.w, a3.x, a3.y, a3.z, a3.w};
        bf16x8 h[16];
#pragma unroll
        for (int j = 0; j < 16; ++j)
            h[j] = *(const bf16x8*)(Xe + (long)e[j] * 128 + c);
#pragma unroll
        for (int j = 0; j < 16; ++j)
#pragma unroll
            for (int q = 0; q < 8; ++q)
                acc[q] += bf16_to_f32((unsigned short)h[j][q]);
    }
    for (; i + 8 <= len; i += 8) {
        ushort4 a0 = *(const ushort4*)(adj + i);
        ushort4 a1 = *(const ushort4*)(adj + i + 4);
        int e[8] = {a0.x, a0.y, a0.z, a0.w, a1.x, a1.y, a1.z, a1.w};
        bf16x8 h[8];
#pragma unroll
        for (int j = 0; j < 8; ++j)
            h[j] = *(const bf16x8*)(Xe + (long)e[j] * 128 + c);
#pragma unroll
        for (int j = 0; j < 8; ++j)
#pragma unroll
            for (int q = 0; q < 8; ++q)
                acc[q] += bf16_to_f32((unsigned short)h[j][q]);
    }
    for (; i + 4 <= len; i += 4) {
        ushort4 a0 = *(const ushort4*)(adj + i);
        int e[4] = {a0.x, a0.y, a0.z, a0.w};
        bf16x8 h[4];
#pragma unroll
        for (int j = 0; j < 4; ++j)
            h[j] = *(const bf16x8*)(Xe + (long)e[j] * 128 + c);
#pragma unroll
        for (int j = 0; j < 4; ++j)
#pragma unroll
            for (int q = 0; q < 8; ++q)
                acc[q] += bf16_to_f32((unsigned short)h[j][q]);
    }
    for (; i < len; ++i) {
        int e = adj[i];
        bf16x8 h = *(const bf16x8*)(Xe + (long)e * 128 + c);
#pragma unroll
        for (int q = 0; q < 8; ++q)
            acc[q] += bf16_to_f32((unsigned short)h[q]);
    }

    float sc = degV[v];
    f32x8 o;
#pragma unroll
    for (int q = 0; q < 8; ++q) o[q] = acc[q] * sc;
    *(f32x8*)(out + (long)v * 128 + c) = o;
}

// ================= kernels =================

// K0: Wt[n][k] = bf16(Wlin[k][n])
__global__ __launch_bounds__(256) void k_init(const float* __restrict__ Wl,
                                              unsigned short* __restrict__ Wt) {
    int idx = blockIdx.x * 256 + threadIdx.x;   // 64 blocks x 256
    if (idx < 128 * 128) {
        int n = idx >> 7, k = idx & 127;
        Wt[idx] = f32_to_bf16(Wl[k * 128 + n]);
    }
}

// K1: gemm (verified body) || histE (single range)
__global__ __launch_bounds__(256) void k_gemm_histE(
    const float* __restrict__ X, const unsigned short* __restrict__ Wt,
    unsigned short* __restrict__ Xp, int nrows, int nGemm,
    const int* __restrict__ keyE, int nnz,
    unsigned int* __restrict__ histE32, int nE4, int che, int nchE)
{
    __shared__ union {
        struct { unsigned short Xs[64 * LDK]; unsigned short Wt[128 * LDK]; } g;
        unsigned int s32[RW];
    } sm;   // 52,224 B -> 3 blocks/CU

    int bid = blockIdx.x;
    const int tid = threadIdx.x;

    if (bid < nGemm) {
        const int row0 = bid * 64;
        for (int base = tid * 4; base < 64 * 128; base += 1024) {
            int r = base >> 7, c = base & 127;
            float4 v = make_float4(0.f, 0.f, 0.f, 0.f);
            if (row0 + r < nrows) v = *(const float4*)(X + (long)(row0 + r) * 128 + c);
            ushort4 h;
            h.x = f32_to_bf16(v.x); h.y = f32_to_bf16(v.y);
            h.z = f32_to_bf16(v.z); h.w = f32_to_bf16(v.w);
            *(ushort4*)(sm.g.Xs + r * LDK + c) = h;
        }
        for (int base = tid * 4; base < 128 * 128; base += 1024) {
            int n = base >> 7, k = base & 127;
            ushort4 h = *(const ushort4*)(Wt + base);
            *(ushort4*)(sm.g.Wt + n * LDK + k) = h;
        }
        __syncthreads();

        const int w    = tid >> 6;
        const int lane = tid & 63;
        const int m    = lane & 15;
        const int quad = lane >> 4;

        f32x4 acc[8];
#pragma unroll
        for (int ct = 0; ct < 8; ++ct) acc[ct] = (f32x4){0.f, 0.f, 0.f, 0.f};

#pragma unroll
        for (int kk = 0; kk < 4; ++kk) {
            bf16x8 a = *(const bf16x8*)(sm.g.Xs + (w * 16 + m) * LDK + kk * 32 + quad * 8);
#pragma unroll
            for (int ct = 0; ct < 8; ++ct) {
                bf16x8 b = *(const bf16x8*)(sm.g.Wt + (ct * 16 + m) * LDK + kk * 32 + quad * 8);
                acc[ct] = __builtin_amdgcn_mfma_f32_16x16x32_bf16(a, b, acc[ct], 0, 0, 0);
            }
        }
#pragma unroll
        for (int ct = 0; ct < 8; ++ct) {
#pragma unroll
            for (int r = 0; r < 4; ++r) {
                int row = row0 + w * 16 + quad * 4 + r;
                if (row < nrows)
                    Xp[(long)row * 128 + ct * 16 + m] = f32_to_bf16(acc[ct][r]);
            }
        }
        return;
    }

    int c = bid - nGemm;
    if (c < nchE)
        hist_body(sm.s32, keyE, nnz, histE32, nE4, che, c, 0, nE4, tid);
}

// K2: scanE || histV (4 ranges, 25KB)
__global__ __launch_bounds__(256) void k_scanE_histV(
    unsigned char* __restrict__ histE8, int* __restrict__ cntE,
    int nE, int nchE, int nScanE,
    const int* __restrict__ keyV, int nnz,
    unsigned int* __restrict__ histV32, int nV4, int chv, int nchV)
{
    __shared__ unsigned int s32[RW];   // 25KB
    int bid = blockIdx.x;
    const int tid = threadIdx.x;
    if (bid < nScanE) {
        int t = bid * 256 + tid;
        if (t < nE) scan_body(histE8, nE, t, nchE, cntE);
        return;
    }
    bid -= nScanE;
    const int c = bid % nchV, r = bid / nchV;
    const int w0 = r * RW;
    int w1 = w0 + RW; if (w1 > nV4) w1 = nV4;
    hist_body(s32, keyV, nnz, histV32, nV4, chv, c, w0, w1, tid);
}

// K3: scatterE (base-in-counter, 25KB) || scanV
__global__ __launch_bounds__(256) void k_scatE_scanV(
    const int* __restrict__ src, const int* __restrict__ dst, int nnz,
    const unsigned char* __restrict__ histE8, int* __restrict__ adjE,
    int nE4, int che, int nchE,
    unsigned char* __restrict__ histV8, int* __restrict__ cntV, int nV, int nchV)
{
    __shared__ unsigned int c32[RW];    // 25KB
    int bid = blockIdx.x;
    const int tid = threadIdx.x;
    if (bid < nchE) {
        const int c = bid;
        const unsigned int* brow = (const unsigned int*)histE8 + (long)c * nE4;
        for (int i = tid; i < nE4; i += 256) c32[i] = brow[i];  // counters = bases
        __syncthreads();
        int e0 = c * che, e1 = e0 + che; if (e1 > nnz) e1 = nnz;
        for (int e = e0 + tid; e < e1; e += 256) {
            int k = dst[e];
            int sh = (k & 3) * 8;
            unsigned int old = atomicAdd(&c32[k >> 2], 1u << sh);
            int slot = (old >> sh) & 0xFF;                      // base + rank
            if (slot < CAPE) adjE[(long)k * CAPE + slot] = src[e];
        }
        return;
    }
    int t = (bid - nchE) * 256 + tid;
    if (t < nV) scan_body(histV8, nV, t, nchV, cntV);
}

// K4: gatherE (16-deep) || scatterV ALL ranges — 25KB LDS
__global__ __launch_bounds__(256) void k_gathE_scatV(
    const unsigned short* __restrict__ Xp, const int* __restrict__ cntE,
    const int* __restrict__ adjE, const float* __restrict__ degE,
    const float* __restrict__ Wbuf, unsigned short* __restrict__ Xe,
    int nE, int nGathE,
    const int* __restrict__ src, const int* __restrict__ dst, int nnz,
    const unsigned char* __restrict__ histV8, unsigned short* __restrict__ adjV,
    int nV4, int chv, int nchV)
{
    __shared__ unsigned int c32[RW];   // 25KB
    int bid = blockIdx.x;
    const int tid = threadIdx.x;
    if (bid < nGathE) {
        gatherE_body(bid, tid, Xp, cntE, adjE, degE, Wbuf, Xe, nE);
        return;
    }
    bid -= nGathE;
    const int c = bid % nchV, r = bid / nchV;   // r in [0, nrV)
    scatV_body(c32, src, dst, nnz, histV8, adjV, nV4, chv, c, r, tid);
}

// K5: gatherV (full range, 16-deep)
__global__ __launch_bounds__(256) void k_gatherV(const unsigned short* __restrict__ Xe,
                                                 const int* __restrict__ cntV,
                                                 const unsigned short* __restrict__ adjV,
                                                 const float* __restrict__ degV,
                                                 float* __restrict__ out,
                                                 int vLo, int vHi) {
    gatherV_body(blockIdx.x, threadIdx.x, Xe, cntV, adjV, degV, out, vLo, vHi);
}

// ---------------- Atomic fallback (round-1, known-good) ----------------
__global__ __launch_bounds__(256) void zero_f4(float4* __restrict__ p, int n4) {
    int i = blockIdx.x * 256 + threadIdx.x;
    if (i < n4) p[i] = make_float4(0.f, 0.f, 0.f, 0.f);
}

__global__ __launch_bounds__(256) void gemm_xw_f32(const float* __restrict__ X,
                                                   const float* __restrict__ Wl,
                                                   float* __restrict__ Xp,
                                                   int nrows) {
    __shared__ float Xs[32 * 128];
    const int tid = threadIdx.x;
    const int row0 = blockIdx.x * 32;
    for (int i = tid * 4; i < 32 * 128; i += 256 * 4) {
        int r = row0 + (i >> 7);
        float4 v = make_float4(0.f, 0.f, 0.f, 0.f);
        if (r < nrows) v = *(const float4*)(X + (long)row0 * 128 + i);
        *(float4*)(Xs + i) = v;
    }
    __syncthreads();
    const int col = tid & 127;
    const int rg  = (tid >> 7) * 16;
    float acc[16];
#pragma unroll
    for (int r = 0; r < 16; ++r) acc[r] = 0.f;
    for (int k = 0; k < 128; k += 4) {
        const float w0 = Wl[(k + 0) * 128 + col];
        const float w1 = Wl[(k + 1) * 128 + col];
        const float w2 = Wl[(k + 2) * 128 + col];
        const float w3 = Wl[(k + 3) * 128 + col];
#pragma unroll
        for (int r = 0; r < 16; ++r) {
            float4 x = *(const float4*)(Xs + (rg + r) * 128 + k);
            acc[r] = fmaf(x.w, w3, fmaf(x.z, w2, fmaf(x.y, w1, fmaf(x.x, w0, acc[r]))));
        }
    }
#pragma unroll
    for (int r = 0; r < 16; ++r) {
        int row = row0 + rg + r;
        if (row < nrows) Xp[(long)row * 128 + col] = acc[r];
    }
}

__global__ __launch_bounds__(256) void scatter_to_hedges(const float* __restrict__ Xp,
                                                         const int* __restrict__ src,
                                                         const int* __restrict__ dst,
                                                         float* __restrict__ Xe,
                                                         int nnz) {
    int t = blockIdx.x * 256 + threadIdx.x;
    int e = t >> 5;
    if (e >= nnz) return;
    int c = (t & 31) << 2;
    int s = src[e], d = dst[e];
    float4 v = *(const float4*)(Xp + (long)s * 128 + c);
    float* o = Xe + (long)d * 128 + c;
    atomicAdd(o + 0, v.x); atomicAdd(o + 1, v.y);
    atomicAdd(o + 2, v.z); atomicAdd(o + 3, v.w);
}

__global__ __launch_bounds__(256) void scatter_to_nodes(const float* __restrict__ Xe,
                                                        const int* __restrict__ src,
                                                        const int* __restrict__ dst,
                                                        const float* __restrict__ degE,
                                                        const float* __restrict__ Wbuf,
                                                        const float* __restrict__ degV,
                                                        float* __restrict__ out,
                                                        int nnz) {
    int t = blockIdx.x * 256 + threadIdx.x;
    int e = t >> 5;
    if (e >= nnz) return;
    int c = (t & 31) << 2;
    int s = src[e], d = dst[e];
    float sc = degE[d] * Wbuf[d] * degV[s];
    float4 v = *(const float4*)(Xe + (long)d * 128 + c);
    float* o = out + (long)s * 128 + c;
    atomicAdd(o + 0, v.x * sc); atomicAdd(o + 1, v.y * sc);
    atomicAdd(o + 2, v.z * sc); atomicAdd(o + 3, v.w * sc);
}

extern "C" void kernel_launch(void* const* d_in, const int* in_sizes, int n_in,
                              void* d_out, int out_size, void* d_ws, size_t ws_size,
                              hipStream_t stream) {
    const float* X    = (const float*)d_in[0];
    const float* Wlin = (const float*)d_in[1];
    const float* degE = (const float*)d_in[2];
    const float* degV = (const float*)d_in[3];
    const float* Wbuf = (const float*)d_in[4];
    const int* g1_src = (const int*)d_in[5];
    const int* g1_dst = (const int*)d_in[6];

    const int nE  = in_sizes[2];   // 25000
    const int nV  = in_sizes[3];   // 100000
    const int nnz = in_sizes[5];   // 1600000

    float* out = (float*)d_out;
    char* ws = (char*)d_ws;

    auto layout_size = [&](int cE, int cV) -> size_t {
        size_t o = 0;
        o += (size_t)nE * CAPE * 4;                 // adjE
        o += (size_t)nV * CAPV * 2;                 // adjV
        o += (size_t)nE * 4 + (size_t)nV * 4;       // cntE, cntV
        size_t he = (size_t)cE * nE;
        size_t xe = (size_t)nE * 128 * 2;
        o += (he > xe) ? he : xe;                   // histE8 (reused as Xe)
        o += (size_t)cV * nV;                       // histV8
        o += 128 * 128 * 2;                         // Wt
        o += 4096;                                  // alignment slack
        return o;
    };

    // launch-width cascade (all values multiples of 16)
    int nchE = 256, nchV = 256;
    if (layout_size(nchE, nchV) > ws_size) { nchE = 256; nchV = 128; }
    if (layout_size(nchE, nchV) > ws_size) { nchE = 128; nchV = 128; }
    if (layout_size(nchE, nchV) > ws_size) { nchE = 64;  nchV = 64;  }

    const int nE4 = nE >> 2, nV4 = nV >> 2;
    const bool eligible = ((nE & 3) == 0) && ((nV & 3) == 0) && (nE4 <= RW) &&
                          layout_size(nchE, nchV) <= ws_size;

    if (eligible) {
        size_t boff = 0;
        auto alloc = [&](size_t bytes) -> char* {
            char* p = ws + boff;
            boff += (bytes + 255) & ~(size_t)255;
            return p;
        };
        int* adjE            = (int*)alloc((size_t)nE * CAPE * 4);
        unsigned short* adjV = (unsigned short*)alloc((size_t)nV * CAPV * 2);
        int* cntE            = (int*)alloc((size_t)nE * 4);
        int* cntV            = (int*)alloc((size_t)nV * 4);
        size_t he = (size_t)nchE * nE;
        size_t xe = (size_t)nE * 128 * 2;
        char* region1         = alloc((he > xe) ? he : xe);
        unsigned char* histE8 = (unsigned char*)region1;
        unsigned short* Xe    = (unsigned short*)region1;  // reused after K3
        unsigned char* histV8 = (unsigned char*)alloc((size_t)nchV * nV);
        unsigned short* Wt    = (unsigned short*)alloc((size_t)128 * 128 * 2);

        unsigned short* Xp_bf = (unsigned short*)d_out;    // staged in d_out

        const int nrV = (nV4 + RW - 1) / RW;               // 4
        const int che = (nnz + nchE - 1) / nchE;
        const int chv = (nnz + nchV - 1) / nchV;

        // K0: Wt transpose
        k_init<<<64, 256, 0, stream>>>(Wlin, Wt);

        // K1: gemm || histE
        int nGemm = (nV + 63) / 64;                        // 1563
        k_gemm_histE<<<nGemm + nchE, 256, 0, stream>>>(
            X, Wt, Xp_bf, nV, nGemm,
            g1_dst, nnz, (unsigned int*)histE8, nE4, che, nchE);

        // K2: scanE || histV (4 ranges)
        int nScanE = (nE + 255) / 256;                     // 98
        k_scanE_histV<<<nScanE + nchV * nrV, 256, 0, stream>>>(
            histE8, cntE, nE, nchE, nScanE,
            g1_src, nnz, (unsigned int*)histV8, nV4, chv, nchV);

        // K3: scatterE || scanV
        int nScanV = (nV + 255) / 256;                     // 391
        k_scatE_scanV<<<nchE + nScanV, 256, 0, stream>>>(
            g1_src, g1_dst, nnz, histE8, adjE, nE4, che, nchE,
            histV8, cntV, nV, nchV);

        // K4: gatherE || scatterV all ranges  (Xe overwrites histE8)
        int nGathE = (nE * 16 + 255) / 256;                // 1563
        k_gathE_scatV<<<nGathE + nchV * nrV, 256, 0, stream>>>(
            Xp_bf, cntE, adjE, degE, Wbuf, Xe, nE, nGathE,
            g1_src, g1_dst, nnz, histV8, adjV, nV4, chv, nchV);

        // K5: gatherV (full)
        int nGathV = (nV * 16 + 255) / 256;                // 6250
        k_gatherV<<<nGathV, 256, 0, stream>>>(Xe, cntV, adjV, degV, out, 0, nV);
    } else {
        // --- atomic fallback (round-1) ---
        float* XeF = (float*)d_ws;
        float* Xp  = out;
        int n4 = nE * 128 / 4;
        zero_f4<<<(n4 + 255) / 256, 256, 0, stream>>>((float4*)XeF, n4);
        gemm_xw_f32<<<(nV + 31) / 32, 256, 0, stream>>>(X, Wlin, Xp, nV);
        long th = (long)nnz * 32;
        scatter_to_hedges<<<(int)((th + 255) / 256), 256, 0, stream>>>(Xp, g1_src, g1_dst,
                                                                       XeF, nnz);
        int m4 = out_size / 4;
        zero_f4<<<(m4 + 255) / 256, 256, 0, stream>>>((float4*)out, m4);
        scatter_to_nodes<<<(int)((th + 255) / 256), 256, 0, stream>>>(XeF, g1_src, g1_dst,
                                                                      degE, Wbuf, degV,
                                                                      out, nnz);
    }
}